// Round 5
// baseline (233.545 us; speedup 1.0000x reference)
//
#include <hip/hip_runtime.h>

// N=64, T=96, F=32, ND=8, D=128. Output = concat( y (N,T,F)=196608 f32, att (F,F)=1024 f32 ).
#define SQKD 0.08838834764831845f  // 1/sqrt(128)

typedef __attribute__((ext_vector_type(8))) short short8;   // 8 bf16 = 4 VGPRs (MFMA A/B frag)
typedef __attribute__((ext_vector_type(4))) float f32x4;    // MFMA C/D frag

__device__ __forceinline__ unsigned short rne_bf16(float f) {
    unsigned u = __float_as_uint(f);
    return (unsigned short)((u + 0x7FFFu + ((u >> 16) & 1u)) >> 16);
}
// Split fp32 into bf16 hi + bf16 lo (RNE): f ~= hi + lo with ~2^-16 rel error.
__device__ __forceinline__ void bf16split(float f, unsigned short& hi, unsigned short& lo) {
    hi = rne_bf16(f);
    float fl = f - __uint_as_float(((unsigned)hi) << 16);
    lo = rne_bf16(fl);
}
__device__ __forceinline__ float bf16lo_f(unsigned v) { return __uint_as_float(v << 16); }
__device__ __forceinline__ float bf16hi_f(unsigned v) { return __uint_as_float(v & 0xFFFF0000u); }

// ---------------------------------------------------------------------------
// K0 prep:
//  blocks 0..63   : split x -> Ahi/Alo[(f*64+n)][t]
//  blocks 64..87  : split+transpose Wbase -> Wth/Wtl[(w*128+d)][t] (Wq scaled)
//  blocks 88..119 : w1 -> bf16 w1b (flat copy)
//  blocks 120..135: w3q[dout][kh*128+d] = bf16(w3[dout][d*8+kh])
// ---------------------------------------------------------------------------
__global__ __launch_bounds__(256) void k_prep(
    const float* __restrict__ x, const float* __restrict__ Wq,
    const float* __restrict__ Wk, const float* __restrict__ Wv,
    const float* __restrict__ w1, const float* __restrict__ w3,
    unsigned short* __restrict__ Ahi, unsigned short* __restrict__ Alo,
    unsigned short* __restrict__ Wth, unsigned short* __restrict__ Wtl,
    unsigned short* __restrict__ w1b, unsigned short* __restrict__ w3q)
{
    __shared__ float s_ws[96 * 129];
    const int tid = threadIdx.x;
    const int bid = blockIdx.x;
    if (bid < 64) {                      // x-split, block = n
        const int n = bid;
        for (int e = tid; e < 3072; e += 256)        // e = t*32+f, coalesced read
            s_ws[(e >> 5) * 33 + (e & 31)] = x[n * 3072 + e];
        __syncthreads();
        const int f = tid >> 3, tg = tid & 7;
#pragma unroll
        for (int j = 0; j < 12; ++j) {
            const int t = tg * 12 + j;
            float v = s_ws[t * 33 + f];
            unsigned short h, l; bf16split(v, h, l);
            Ahi[(f * 64 + n) * 96 + t] = h;
            Alo[(f * 64 + n) * 96 + t] = l;
        }
    } else if (bid < 88) {               // W-split, block = (sel,kh)
        const int w = bid - 64;          // 0..23
        const int sel = w >> 3, kh = w & 7;
        const float* src = (sel == 0 ? Wq : sel == 1 ? Wk : Wv) + kh * 12288;
        for (int e = tid; e < 12288; e += 256)       // e = t*128+d, coalesced
            s_ws[(e >> 7) * 129 + (e & 127)] = src[e];
        __syncthreads();
        const int d = tid >> 1, th = tid & 1;
        const float sc = (sel == 0) ? SQKD : 1.0f;
#pragma unroll
        for (int j = 0; j < 48; ++j) {
            const int t = th * 48 + j;
            float v = s_ws[t * 129 + d] * sc;
            unsigned short h, l; bf16split(v, h, l);
            Wth[(w * 128 + d) * 96 + t] = h;
            Wtl[(w * 128 + d) * 96 + t] = l;
        }
    } else if (bid < 120) {              // w1 -> bf16, flat
        const int base = (bid - 88) * 8192;
#pragma unroll
        for (int it = 0; it < 32; ++it) {
            const int i = base + it * 256 + tid;
            w1b[i] = rne_bf16(w1[i]);
        }
    } else {                             // w3 permute -> bf16
        const int base = (bid - 120) * 8192;
#pragma unroll
        for (int it = 0; it < 32; ++it) {
            const int o = base + it * 256 + tid;     // o = dout*1024 + kh*128 + d
            const int dout = o >> 10, kk = o & 1023;
            const int kh = kk >> 7, d = kk & 127;
            w3q[o] = rne_bf16(w3[dout * 1024 + d * 8 + kh]);
        }
    }
}

// ---------------------------------------------------------------------------
// K1: QKV via MFMA. grid (f=32, nh=2, b24=24: sel*8+kh). Per block:
// D[64n x 64d] = A[64 x 96] @ W[96 x 64], 3-term bf16 split = fp32-accurate.
// Q/K written pre-split hi/lo; V written single bf16.
// ---------------------------------------------------------------------------
__global__ __launch_bounds__(256) void k_qkvg(
    const unsigned short* __restrict__ Ahi, const unsigned short* __restrict__ Alo,
    const unsigned short* __restrict__ Wth, const unsigned short* __restrict__ Wtl,
    const float* __restrict__ bq, const float* __restrict__ bk, const float* __restrict__ bv,
    unsigned short* __restrict__ qhi, unsigned short* __restrict__ qlo,
    unsigned short* __restrict__ khi, unsigned short* __restrict__ klo,
    unsigned short* __restrict__ V16)
{
    __shared__ __align__(16) unsigned short sAh[64 * 96], sAl[64 * 96];
    __shared__ __align__(16) unsigned short sBh[64 * 96], sBl[64 * 96];
    const int tid = threadIdx.x;
    const int f = blockIdx.x, nh = blockIdx.y, b24 = blockIdx.z;
    const int sel = b24 >> 3, kh = b24 & 7;

    const unsigned short* gAh = Ahi + f * 6144;
    const unsigned short* gAl = Alo + f * 6144;
    const unsigned short* gBh = Wth + (b24 * 128 + nh * 64) * 96;
    const unsigned short* gBl = Wtl + (b24 * 128 + nh * 64) * 96;
#pragma unroll
    for (int it = 0; it < 3; ++it) {
        const int off = (it * 256 + tid) * 8;
        *(short8*)(sAh + off) = *(const short8*)(gAh + off);
        *(short8*)(sAl + off) = *(const short8*)(gAl + off);
        *(short8*)(sBh + off) = *(const short8*)(gBh + off);
        *(short8*)(sBl + off) = *(const short8*)(gBl + off);
    }
    __syncthreads();

    const int lane = tid & 63, wid = tid >> 6;
    const int quad = lane >> 4, col = lane & 15;
    f32x4 acc[4];
#pragma unroll
    for (int nt = 0; nt < 4; ++nt)
#pragma unroll
        for (int r = 0; r < 4; ++r) acc[nt][r] = 0.f;

#pragma unroll
    for (int ks = 0; ks < 3; ++ks) {
        const int ko = ks * 32 + quad * 8;
        short8 ah = *(const short8*)(sAh + (wid * 16 + col) * 96 + ko);
        short8 al = *(const short8*)(sAl + (wid * 16 + col) * 96 + ko);
#pragma unroll
        for (int nt = 0; nt < 4; ++nt) {
            short8 bh = *(const short8*)(sBh + (nt * 16 + col) * 96 + ko);
            short8 bl = *(const short8*)(sBl + (nt * 16 + col) * 96 + ko);
            acc[nt] = __builtin_amdgcn_mfma_f32_16x16x32_bf16(ah, bh, acc[nt], 0, 0, 0);
            acc[nt] = __builtin_amdgcn_mfma_f32_16x16x32_bf16(al, bh, acc[nt], 0, 0, 0);
            acc[nt] = __builtin_amdgcn_mfma_f32_16x16x32_bf16(ah, bl, acc[nt], 0, 0, 0);
        }
    }

    const int b = f * 8 + kh;
    const float* bias = sel == 0 ? bq : sel == 1 ? bk : bv;
    const float bsc = (sel == 0) ? SQKD : 1.0f;
#pragma unroll
    for (int nt = 0; nt < 4; ++nt) {
        const int d = nh * 64 + nt * 16 + col;
        const float bb = bias[b * 128 + d] * bsc;
#pragma unroll
        for (int r = 0; r < 4; ++r) {
            const int n = wid * 16 + quad * 4 + r;
            const float v = acc[nt][r] + bb;
            const int o = (b * 64 + n) * 128 + d;
            if (sel == 2) V16[o] = rne_bf16(v);
            else if (sel == 0) { unsigned short h, l; bf16split(v, h, l); qhi[o] = h; qlo[o] = l; }
            else               { unsigned short h, l; bf16split(v, h, l); khi[o] = h; klo[o] = l; }
        }
    }
}

// ---------------------------------------------------------------------------
// K2 (hot): 1f x 1g per block, 1024 blocks, 4 waves (wsub=n-half, wm=m-half).
// S = Q@K^T via 3-term split MFMA (fp32-accurate); S kept fp32 in LDS
// (stride 68: write conflicts 2-way = free); contraction vs bf16 w1.
// LDS ~37.9 KB -> 4 blocks/CU (16 waves/CU).
// ---------------------------------------------------------------------------
__global__ __launch_bounds__(256, 4) void k_scores(
    const unsigned short* __restrict__ qhi, const unsigned short* __restrict__ qlo,
    const unsigned short* __restrict__ khi, const unsigned short* __restrict__ klo,
    const unsigned short* __restrict__ w1b, float* __restrict__ H)
{
    __shared__ __align__(16) unsigned short sQhi[64 * 40];
    __shared__ __align__(16) unsigned short sQlo[64 * 40];
    __shared__ __align__(16) unsigned short sKhi[64 * 40];
    __shared__ __align__(16) unsigned short sKlo[64 * 40];
    __shared__ __align__(16) float sS[64 * 68];             // S fp32, stride 68

    const int tid  = threadIdx.x;
    const int lane = tid & 63, wid = tid >> 6;
    const int quad = lane >> 4, col = lane & 15;
    const int f = blockIdx.x >> 5;
    const int g = blockIdx.x & 31;
    const int wsub = wid & 1;          // n-half
    const int wm   = wid >> 1;         // m-half

    float he[8];
#pragma unroll
    for (int e = 0; e < 8; ++e) he[e] = 0.f;

    for (int kh = 0; kh < 8; ++kh) {
        f32x4 acc[2][2];
#pragma unroll
        for (int ti = 0; ti < 2; ++ti)
#pragma unroll
            for (int tj = 0; tj < 2; ++tj)
#pragma unroll
                for (int r = 0; r < 4; ++r) acc[ti][tj][r] = 0.f;

        for (int ch = 0; ch < 4; ++ch) {
            __syncthreads();
            {   // stage Q/K hi/lo chunk: 64 rows x 4 granules(8 ush) each
                const int r = tid >> 2, gg = tid & 3;
                const long qoff = (long)(f * 8 + kh) * 8192 + r * 128 + ch * 32 + gg * 8;
                const long koff = (long)(g * 8 + kh) * 8192 + r * 128 + ch * 32 + gg * 8;
                const int doff = r * 40 + gg * 8;
                *(short8*)(sQhi + doff) = *(const short8*)(qhi + qoff);
                *(short8*)(sQlo + doff) = *(const short8*)(qlo + qoff);
                *(short8*)(sKhi + doff) = *(const short8*)(khi + koff);
                *(short8*)(sKlo + doff) = *(const short8*)(klo + koff);
            }
            __syncthreads();

            short8 ah[2], al[2], bh[2], bl[2];
#pragma unroll
            for (int t = 0; t < 2; ++t) {
                const int offq = ((wsub * 2 + t) * 16 + col) * 40 + quad * 8;
                ah[t] = *(const short8*)(sQhi + offq);
                al[t] = *(const short8*)(sQlo + offq);
                const int offk = ((wm * 2 + t) * 16 + col) * 40 + quad * 8;
                bh[t] = *(const short8*)(sKhi + offk);
                bl[t] = *(const short8*)(sKlo + offk);
            }
#pragma unroll
            for (int ti = 0; ti < 2; ++ti)
#pragma unroll
                for (int tj = 0; tj < 2; ++tj) {
                    acc[ti][tj] = __builtin_amdgcn_mfma_f32_16x16x32_bf16(ah[ti], bh[tj], acc[ti][tj], 0, 0, 0);
                    acc[ti][tj] = __builtin_amdgcn_mfma_f32_16x16x32_bf16(al[ti], bh[tj], acc[ti][tj], 0, 0, 0);
                    acc[ti][tj] = __builtin_amdgcn_mfma_f32_16x16x32_bf16(ah[ti], bl[tj], acc[ti][tj], 0, 0, 0);
                }
        }

        // S -> fp32 LDS (C-layout: n = ntile*16+quad*4+r, m = mtile*16+col)
#pragma unroll
        for (int ti = 0; ti < 2; ++ti)
#pragma unroll
            for (int tj = 0; tj < 2; ++tj)
#pragma unroll
                for (int r = 0; r < 4; ++r) {
                    const int n = (wsub * 2 + ti) * 16 + quad * 4 + r;
                    const int m = (wm * 2 + tj) * 16 + col;
                    sS[n * 68 + m] = acc[ti][tj][r];
                }
        __syncthreads();

        // contraction: he[e] += sum_p S[p] * w1b[e, kh*4096 + p]
        const unsigned short* w1k = w1b + kh * 4096;
#pragma unroll
        for (int i = 0; i < 4; ++i) {
            const int p = i * 1024 + tid * 4;
            const int n = p >> 6, m = p & 63;
            f32x4 s = *(const f32x4*)(sS + n * 68 + m);
#pragma unroll
            for (int e = 0; e < 8; ++e) {
                uint2 wv = *(const uint2*)(w1k + e * 32768 + p);
                he[e] += s.x * bf16lo_f(wv.x) + s.y * bf16hi_f(wv.x)
                       + s.z * bf16lo_f(wv.y) + s.w * bf16hi_f(wv.y);
            }
        }
    }

    __syncthreads();                    // sS reads done; reuse as reduction buf
    float* red = sS;
#pragma unroll
    for (int e = 0; e < 8; ++e) {
        float v = he[e];
        v += __shfl_down(v, 32); v += __shfl_down(v, 16); v += __shfl_down(v, 8);
        v += __shfl_down(v, 4);  v += __shfl_down(v, 2);  v += __shfl_down(v, 1);
        if (lane == 0) red[wid * 8 + e] = v;
    }
    __syncthreads();
    if (tid < 8)
        H[blockIdx.x * 8 + tid] = red[tid] + red[8 + tid] + red[16 + tid] + red[24 + tid];
}

// ---------------------------------------------------------------------------
// K3: logits = relu(H + b1) @ w2 + b2 ; att = softmax over g. 1 block.
// ---------------------------------------------------------------------------
__global__ void k_soft(const float* __restrict__ H, const float* __restrict__ b1,
                       const float* __restrict__ w2, const float* __restrict__ b2,
                       float* __restrict__ att)
{
    __shared__ float lg[1024];
    const int tid = threadIdx.x;       // 1024
    {
        float s = b2[0];
        const float* h = H + tid * 8;
#pragma unroll
        for (int e = 0; e < 8; ++e) s += fmaxf(h[e] + b1[e], 0.f) * w2[e];
        lg[tid] = s;
    }
    __syncthreads();
    if (tid < 32) {
        float mx = -1e30f;
        for (int g2 = 0; g2 < 32; ++g2) mx = fmaxf(mx, lg[tid * 32 + g2]);
        float sum = 0.f;
        for (int g2 = 0; g2 < 32; ++g2) sum += expf(lg[tid * 32 + g2] - mx);
        float inv = 1.f / sum;
        for (int g2 = 0; g2 < 32; ++g2) att[tid * 32 + g2] = expf(lg[tid * 32 + g2] - mx) * inv;
    }
}

// ---------------------------------------------------------------------------
// K4: Z[j,n,dout] = sum_{kh,d} V16[j,kh,n,d] * w3q[dout, kh*128+d] via MFMA.
// 32 blocks (j), 4 waves (wave = n-tile). att-independent.
// ---------------------------------------------------------------------------
__global__ __launch_bounds__(256) void k_z(
    const unsigned short* __restrict__ V16, const unsigned short* __restrict__ w3q,
    float* __restrict__ Z)
{
    __shared__ __align__(16) unsigned short sA[64 * 136];    // V plane, row n
    __shared__ __align__(16) unsigned short sB[128 * 136];   // w3q rows dout, k-chunk
    const int tid = threadIdx.x;
    const int j = blockIdx.x;
    const int lane = tid & 63, wid = tid >> 6;
    const int quad = lane >> 4, col = lane & 15;

    f32x4 acc[8];
#pragma unroll
    for (int dt = 0; dt < 8; ++dt)
#pragma unroll
        for (int r = 0; r < 4; ++r) acc[dt][r] = 0.f;

    for (int kh = 0; kh < 8; ++kh) {
        __syncthreads();
        {   // stage V[j,kh] : 64 rows x 16 granules  (1024 granules total)
            const unsigned short* plane = V16 + (long)(j * 8 + kh) * 8192;
#pragma unroll
            for (int it = 0; it < 4; ++it) {
                const int gdx = it * 256 + tid;
                const int n = gdx >> 4, c = gdx & 15;
                *(short8*)(sA + n * 136 + c * 8) = *(const short8*)(plane + n * 128 + c * 8);
            }
            // stage w3q chunk: 128 rows x 16 granules
#pragma unroll
            for (int it = 0; it < 8; ++it) {
                const int gdx = it * 256 + tid;
                const int row = gdx >> 4, c = gdx & 15;
                *(short8*)(sB + row * 136 + c * 8) =
                    *(const short8*)(w3q + row * 1024 + kh * 128 + c * 8);
            }
        }
        __syncthreads();

#pragma unroll
        for (int ks = 0; ks < 4; ++ks) {
            short8 a = *(const short8*)(sA + (wid * 16 + col) * 136 + ks * 32 + quad * 8);
#pragma unroll
            for (int dt = 0; dt < 8; ++dt) {
                short8 b = *(const short8*)(sB + (dt * 16 + col) * 136 + ks * 32 + quad * 8);
                acc[dt] = __builtin_amdgcn_mfma_f32_16x16x32_bf16(a, b, acc[dt], 0, 0, 0);
            }
        }
    }

#pragma unroll
    for (int dt = 0; dt < 8; ++dt)
#pragma unroll
        for (int r = 0; r < 4; ++r) {
            const int n = wid * 16 + quad * 4 + r;
            const int dout = dt * 16 + col;
            Z[(j * 64 + n) * 128 + dout] = acc[dt][r];
        }
}

// ---------------------------------------------------------------------------
// K5: per n: y1[f,dout] = relu(b3 + sum_j att[f,j] Z[j,n,dout]);
//           out[n,t,f] = b4[t] + sum_d y1[f,d] w4[t,d].  64 blocks x 256.
// ---------------------------------------------------------------------------
__global__ __launch_bounds__(256) void k_y(
    const float* __restrict__ Z, const float* __restrict__ att,
    const float* __restrict__ b3, const float* __restrict__ w4,
    const float* __restrict__ b4, float* __restrict__ out)
{
    __shared__ __align__(16) float Zs[32 * 128];     // Z[:, n, :]
    __shared__ float atts[1024];
    __shared__ __align__(16) float y1s[32 * 132];    // padded stride
    const int n = blockIdx.x;
    const int tid = threadIdx.x;

#pragma unroll
    for (int it = 0; it < 4; ++it) {
        const int gdx = it * 256 + tid;              // f32x4 granule / att elem
        const int j = gdx >> 5, c = gdx & 31;
        *(f32x4*)(Zs + j * 128 + c * 4) = *(const f32x4*)(Z + j * 8192 + n * 128 + c * 4);
        atts[gdx] = att[gdx];
    }
    __syncthreads();

    {   // phase 1: thread = (f, dout/16-group)
        const int ff = tid >> 3, l8 = tid & 7;
        f32x4 a4[4];
#pragma unroll
        for (int v = 0; v < 4; ++v) a4[v] = *(const f32x4*)(b3 + l8 * 16 + v * 4);
        for (int j = 0; j < 32; ++j) {
            const float a = atts[ff * 32 + j];
#pragma unroll
            for (int v = 0; v < 4; ++v) {
                f32x4 z = *(const f32x4*)(Zs + j * 128 + l8 * 16 + v * 4);
                a4[v].x += a * z.x; a4[v].y += a * z.y;
                a4[v].z += a * z.z; a4[v].w += a * z.w;
            }
        }
#pragma unroll
        for (int v = 0; v < 4; ++v) {
            f32x4 r;
            r.x = fmaxf(a4[v].x, 0.f); r.y = fmaxf(a4[v].y, 0.f);
            r.z = fmaxf(a4[v].z, 0.f); r.w = fmaxf(a4[v].w, 0.f);
            *(f32x4*)(y1s + ff * 132 + l8 * 16 + v * 4) = r;
        }
    }
    __syncthreads();

#pragma unroll
    for (int it = 0; it < 12; ++it) {    // phase 2: o = t*32+f, coalesced out
        const int o = it * 256 + tid;
        const int t = o >> 5, ff = o & 31;
        float s = b4[t];
        const float* w4r = w4 + t * 128;
        const float* y1r = y1s + ff * 132;
        for (int d4 = 0; d4 < 32; ++d4) {
            f32x4 w = *(const f32x4*)(w4r + d4 * 4);
            f32x4 y = *(const f32x4*)(y1r + d4 * 4);
            s += y.x * w.x + y.y * w.y + y.z * w.z + y.w * w.w;
        }
        out[n * 3072 + o] = s;
    }
}

// ---------------------------------------------------------------------------
extern "C" void kernel_launch(void* const* d_in, const int* in_sizes, int n_in,
                              void* d_out, int out_size, void* d_ws, size_t ws_size,
                              hipStream_t stream)
{
    const float* x  = (const float*)d_in[0];
    const float* Wq = (const float*)d_in[1];
    const float* Wk = (const float*)d_in[2];
    const float* Wv = (const float*)d_in[3];
    const float* bq = (const float*)d_in[4];
    const float* bk = (const float*)d_in[5];
    const float* bv = (const float*)d_in[6];
    const float* w1 = (const float*)d_in[7];
    const float* b1 = (const float*)d_in[8];
    const float* w2 = (const float*)d_in[9];
    const float* b2 = (const float*)d_in[10];
    const float* w3 = (const float*)d_in[11];
    const float* b3 = (const float*)d_in[12];
    const float* w4 = (const float*)d_in[13];
    const float* b4 = (const float*)d_in[14];

    float* out = (float*)d_out;
    char*  wb  = (char*)d_ws;
    unsigned short* qhi = (unsigned short*)(wb + 0x0000000);   // 4 MB
    unsigned short* qlo = (unsigned short*)(wb + 0x0400000);   // 4 MB
    unsigned short* khi = (unsigned short*)(wb + 0x0800000);   // 4 MB
    unsigned short* klo = (unsigned short*)(wb + 0x0C00000);   // 4 MB
    unsigned short* V16 = (unsigned short*)(wb + 0x1000000);   // 4 MB
    float*          Hb  = (float*)        (wb + 0x1400000);    // 32 KB
    unsigned short* Ahi = (unsigned short*)(wb + 0x1410000);   // 384 KB
    unsigned short* Alo = (unsigned short*)(wb + 0x1470000);   // 384 KB
    unsigned short* Wth = (unsigned short*)(wb + 0x14D0000);   // 576 KB
    unsigned short* Wtl = (unsigned short*)(wb + 0x1560000);   // 576 KB
    unsigned short* w1b = (unsigned short*)(wb + 0x15F0000);   // 512 KB
    unsigned short* w3q = (unsigned short*)(wb + 0x1670000);   // 256 KB
    float*          Zb  = (float*)        (wb + 0x16B0000);    // 1 MB  (end ~24.8 MB)
    float* att = out + 196608;

    k_prep  <<<136, 256, 0, stream>>>(x, Wq, Wk, Wv, w1, w3, Ahi, Alo, Wth, Wtl, w1b, w3q);
    k_qkvg  <<<dim3(32, 2, 24), 256, 0, stream>>>(Ahi, Alo, Wth, Wtl, bq, bk, bv,
                                                  qhi, qlo, khi, klo, V16);
    k_z     <<<32, 256, 0, stream>>>(V16, w3q, Zb);
    k_scores<<<1024, 256, 0, stream>>>(qhi, qlo, khi, klo, w1b, Hb);
    k_soft  <<<1, 1024, 0, stream>>>(Hb, b1, w2, b2, att);
    k_y     <<<64, 256, 0, stream>>>(Zb, att, b3, w4, b4, out);
}